// Round 6
// baseline (240.624 us; speedup 1.0000x reference)
//
#include <hip/hip_runtime.h>
#include <hip/hip_bf16.h>

// B,N,D,H = 4,2048,512,8 (DK=64). fp32 I/O; bf16 intermediates in ws.
// v9: single path (old Path B layout, 43.0 MB ws): cvt4 eliminated -
// proj1 stages X from fp32 directly (INK=0; X panels are XCD-pinned so
// re-reads hit L2; saves the whole 75MB cvt pass + a launch). attn = v6
// (proven 104-105us) with Ps writes f2bf_fast (v7-validated numerics).
// proj2 = 128x64 tile, 512 blocks = 2 blocks/CU (R5-proven).
#define B_  4
#define N_  2048
#define D_  512
#define H_  8

typedef unsigned short u16;
typedef __attribute__((ext_vector_type(8))) unsigned short ushort8;
typedef __attribute__((ext_vector_type(4))) unsigned short us4;
typedef __attribute__((ext_vector_type(8))) short short8;
typedef __attribute__((ext_vector_type(4))) float float4v;

__device__ __forceinline__ float bf2f(u16 u) {
    union { unsigned int i; float f; } v;
    v.i = ((unsigned int)u) << 16;
    return v.f;
}
__device__ __forceinline__ u16 f2bf(float f) {          // RNE
    union { float f; unsigned int i; } v;
    v.f = f;
    unsigned int r = v.i + 0x7FFFu + ((v.i >> 16) & 1u);
    return (u16)(r >> 16);
}
__device__ __forceinline__ u16 f2bf_fast(float f) {     // round-half-up
    union { float f; unsigned int i; } v;
    v.f = f;
    return (u16)((v.i + 0x8000u) >> 16);
}

// async global->LDS, 16B/lane, dest = wave-uniform base + lane*16 (m104 rule)
__device__ __forceinline__ void gload_lds16(const void* g, void* l) {
    __builtin_amdgcn_global_load_lds(
        (const __attribute__((address_space(1))) unsigned int*)g,
        (__attribute__((address_space(3))) unsigned int*)l, 16, 0, 0);
}

#define WAIT_VM(N) do { \
    asm volatile("s_waitcnt vmcnt(" #N ")" ::: "memory"); \
    __builtin_amdgcn_sched_barrier(0); } while (0)
#define WAIT_LGKM0 do { \
    asm volatile("s_waitcnt lgkmcnt(0)" ::: "memory"); \
    __builtin_amdgcn_sched_barrier(0); } while (0)
#define BARRIER do { \
    __builtin_amdgcn_s_barrier(); \
    __builtin_amdgcn_sched_barrier(0); } while (0)

// ---------------------------------------------------------------------------
// wconv: Wq,Wo fp32 -> bf16, out = [Wqb | Wob]. grid (128, 2) x 256.
// ---------------------------------------------------------------------------
__global__ __launch_bounds__(256) void wconv(
    const float* __restrict__ Wq, const float* __restrict__ Wo,
    u16* __restrict__ out)
{
    const int idx = (blockIdx.x * 256 + threadIdx.x) * 8;
    const float* src = blockIdx.y ? Wo : Wq;
    u16* dst = out + (size_t)blockIdx.y * (D_ * D_) + idx;
    float4v a = *(const float4v*)(src + idx);
    float4v b = *(const float4v*)(src + idx + 4);
    ushort8 o;
    #pragma unroll
    for (int j = 0; j < 4; ++j) { o[j] = f2bf(a[j]); o[j + 4] = f2bf(b[j]); }
    *(ushort8*)dst = o;
}

// ---------------------------------------------------------------------------
// proj1_mfma: Xp[z] = X[z] @ Wq^T + bq for z in {Q,K,V}; X fp32 in-staging
// cvt (no separate cvt pass; X panel L2-resident per XCD). W bf16 via gload.
// Out bf16; z==2 stores transposed Vpt[b][e][n].
// 128x128 tile, 4 waves x 4x4 MFMA 16x16x32, BK=32. grid 768 (3 blocks/CU).
// XCD swizzle: flat&7 = (z,m) low bits so the 4 e-tiles of one X-panel
// share an XCD.
// ---------------------------------------------------------------------------
__global__ __launch_bounds__(256) void proj1_mfma(
    const float* __restrict__ X0, const float* __restrict__ X1,
    const float* __restrict__ X2, const u16* __restrict__ Wb,
    const float* __restrict__ bias, u16* __restrict__ C0)
{
    __shared__ u16 As[128][32];
    __shared__ u16 Bs[128][32];

    const int t = threadIdx.x;
    const int flat = blockIdx.x;
    const int xcd = flat & 7, rr = flat >> 3;
    const int eb = rr & 3, g = rr >> 2;
    const int zm = xcd + 8 * g;          // 0 .. 191
    const int z  = zm >> 6;
    const int e0 = eb * 128;
    const int m0 = (zm & 63) * 128;

    const float* X = (z == 0) ? X0 : ((z == 1) ? X1 : X2);
    const int w = t >> 6, l = t & 63;
    const int lane16 = l & 15, quad = l >> 4;
    const int wr = (w >> 1) * 64;
    const int wc = (w & 1) * 64;

    float4v acc[4][4];
    #pragma unroll
    for (int i = 0; i < 4; ++i)
        #pragma unroll
        for (int j = 0; j < 4; ++j)
            acc[i][j] = (float4v){0.f, 0.f, 0.f, 0.f};

    for (int k0 = 0; k0 < 512; k0 += 32) {
        __syncthreads();

        // ---- stage A tile: fp32 X -> bf16 (VALU cvt) ----
        #pragma unroll
        for (int i = 0; i < 2; ++i) {
            int v   = t + 256 * i;
            int row = v >> 2;
            int c8  = (v & 3) * 8;
            const float* xp = X + (size_t)(m0 + row) * 512 + k0 + c8;
            float4v x0 = *(const float4v*)xp;
            float4v x1 = *(const float4v*)(xp + 4);
            ushort8 o;
            #pragma unroll
            for (int j = 0; j < 4; ++j) {
                o[j]     = f2bf_fast(x0[j]);
                o[j + 4] = f2bf_fast(x1[j]);
            }
            *(ushort8*)&As[row][c8] = o;
        }

        // ---- stage B tile (W, bf16 via gload) ----
        #pragma unroll
        for (int i = 0; i < 2; ++i) {
            int r0 = w * 32 + i * 16;
            gload_lds16(Wb + (size_t)(e0 + r0 + (l >> 2)) * 512 + k0 + (l & 3) * 8,
                        &Bs[r0][0]);
        }
        __syncthreads();

        short8 af[4], bfr[4];
        #pragma unroll
        for (int i = 0; i < 4; ++i)
            af[i] = *(const short8*)&As[wr + i * 16 + lane16][quad * 8];
        #pragma unroll
        for (int j = 0; j < 4; ++j)
            bfr[j] = *(const short8*)&Bs[wc + j * 16 + lane16][quad * 8];
        #pragma unroll
        for (int i = 0; i < 4; ++i)
            #pragma unroll
            for (int j = 0; j < 4; ++j)
                acc[i][j] = __builtin_amdgcn_mfma_f32_16x16x32_bf16(
                    af[i], bfr[j], acc[i][j], 0, 0, 0);
    }

    float bj[4];
    #pragma unroll
    for (int j = 0; j < 4; ++j) bj[j] = bias[e0 + wc + j * 16 + lane16];

    if (z == 2) {   // transposed store: Vpt[b][e][n]
        u16* C = C0 + 2 * (size_t)B_ * N_ * D_;
        #pragma unroll
        for (int i = 0; i < 4; ++i) {
            int mrow = m0 + wr + i * 16 + quad * 4;
            int bb = mrow >> 11, nb = mrow & (N_ - 1);
            #pragma unroll
            for (int j = 0; j < 4; ++j) {
                int e = e0 + wc + j * 16 + lane16;
                us4 o;
                #pragma unroll
                for (int r = 0; r < 4; ++r) o[r] = f2bf(acc[i][j][r] + bj[j]);
                *(us4*)(C + (size_t)(bb * D_ + e) * N_ + nb) = o;
            }
        }
    } else {
        u16* C = C0 + (size_t)z * (size_t)B_ * N_ * D_;
        #pragma unroll
        for (int i = 0; i < 4; ++i)
            #pragma unroll
            for (int j = 0; j < 4; ++j) {
                int e = e0 + wc + j * 16 + lane16;
                #pragma unroll
                for (int r = 0; r < 4; ++r) {
                    int mrow = m0 + wr + i * 16 + quad * 4 + r;
                    C[(size_t)mrow * D_ + e] = f2bf(acc[i][j][r] + bj[j]);
                }
            }
    }
}

// ---------------------------------------------------------------------------
// proj2_mfma: out[8192,512] = (P0+P1) @ Wo^T + bo, fp32 out.
// 128x64 tile -> 512 blocks = 2 blocks/CU (cross-block overlap hides the
// barrier drains). 4 waves, each owns 64x32 (acc 4x2), BK=32, LDS 12 KB.
// ---------------------------------------------------------------------------
__global__ __launch_bounds__(256) void proj2_mfma(
    const u16* __restrict__ P0, const u16* __restrict__ P1,
    const u16* __restrict__ Wv, const float* __restrict__ bias,
    float* __restrict__ C)
{
    __shared__ u16 As[128][32];
    __shared__ u16 Bs[64][32];

    const int t = threadIdx.x;
    const int flat = blockIdx.x;
    const int xcd = flat & 7, rr = flat >> 3;
    const int eb = rr & 7, g = rr >> 3;
    const int m0 = (xcd + 8 * g) * 128;
    const int e0 = eb * 64;

    const int w = t >> 6, l = t & 63;
    const int lane16 = l & 15, quad = l >> 4;
    const int wr = (w >> 1) * 64;
    const int wc = (w & 1) * 32;

    float4v acc[4][2];
    #pragma unroll
    for (int i = 0; i < 4; ++i)
        #pragma unroll
        for (int j = 0; j < 2; ++j)
            acc[i][j] = (float4v){0.f, 0.f, 0.f, 0.f};

    for (int k0 = 0; k0 < 512; k0 += 32) {
        __syncthreads();

        // ---- stage A = P0 + P1 (bf16 partial sums) ----
        #pragma unroll
        for (int i = 0; i < 2; ++i) {
            int v   = t + 256 * i;
            int row = v >> 2;
            int c8  = (v & 3) * 8;
            size_t gi = (size_t)(m0 + row) * 512 + k0 + c8;
            ushort8 a = *(const ushort8*)(P0 + gi);
            ushort8 b = *(const ushort8*)(P1 + gi);
            ushort8 o;
            #pragma unroll
            for (int j = 0; j < 8; ++j) o[j] = f2bf(bf2f(a[j]) + bf2f(b[j]));
            *(ushort8*)&As[row][c8] = o;
        }

        // ---- stage B tile (W, bf16 via gload; 64 rows = 1 gload/wave) ----
        gload_lds16(Wv + (size_t)(e0 + w * 16 + (l >> 2)) * 512 + k0 + (l & 3) * 8,
                    &Bs[w * 16][0]);
        __syncthreads();

        short8 af[4], bfr[2];
        #pragma unroll
        for (int i = 0; i < 4; ++i)
            af[i] = *(const short8*)&As[wr + i * 16 + lane16][quad * 8];
        #pragma unroll
        for (int j = 0; j < 2; ++j)
            bfr[j] = *(const short8*)&Bs[wc + j * 16 + lane16][quad * 8];
        #pragma unroll
        for (int i = 0; i < 4; ++i)
            #pragma unroll
            for (int j = 0; j < 2; ++j)
                acc[i][j] = __builtin_amdgcn_mfma_f32_16x16x32_bf16(
                    af[i], bfr[j], acc[i][j], 0, 0, 0);
    }

    float bj[2];
    #pragma unroll
    for (int j = 0; j < 2; ++j) bj[j] = bias[e0 + wc + j * 16 + lane16];

    #pragma unroll
    for (int i = 0; i < 4; ++i)
        #pragma unroll
        for (int j = 0; j < 2; ++j) {
            int e = e0 + wc + j * 16 + lane16;
            #pragma unroll
            for (int r = 0; r < 4; ++r) {
                int mrow = m0 + wr + i * 16 + quad * 4 + r;
                C[(size_t)mrow * D_ + e] = acc[i][j][r] + bj[j];
            }
        }
}

// ---------------------------------------------------------------------------
// attn v6 (proven 104-105us): 512 thr = 8 waves (ns owns 16 n-rows, ms
// splits the 32-m chunk). Counted-vmcnt pipeline, per chunk c:
//   VM(4) drain V-reg loads(c); commit Vs; QK(c) from Ks[c&1]; register
//   heads-softmax -> Ps (f2bf_fast); issue V-reg loads(c+1); LGKM0+BAR;
//   issue Kg(c+2) -> Ks[c&1]; PV(c); VM(8) drain Kg(c+1); LGKM0+BAR.
// Vs/Ps stride 36 u16 (conflict-free). LDS 140,288 B. grid 256, flat&7=(b,z).
// ---------------------------------------------------------------------------
__global__ __launch_bounds__(512, 2) void attn_mfma6(
    const u16* __restrict__ Qp, const u16* __restrict__ Kp,
    const u16* __restrict__ Vpt, u16* __restrict__ A0)
{
    __shared__ u16 Ks[2][32][520];     // 66,560 B double-buffered K
    __shared__ u16 Vs[512][36];        // 36,864 B (stride-36: clean banks)
    __shared__ u16 Ps[4][8][16][36];   // 36,864 B pair-shared P per n-tile

    const int t = threadIdx.x;
    const int w = t >> 6, l = t & 63;
    const int lane16 = l & 15, quad = l >> 4;
    const int ns = w >> 1, ms = w & 1;

    const int flat = blockIdx.x;
    const int xcd  = flat & 7;
    const int b = xcd >> 1;            // (b, z) pinned to one XCD
    const int z = xcd & 1;
    const int n0 = (flat >> 3) * 64 + ns * 16;   // this wave-pair's 16 rows
    const int seg  = N_ / 2;
    const int mbeg = z * seg;
    u16* A = A0 + (size_t)z * ((size_t)B_ * N_ * D_);

    const u16* Kb = Kp + (size_t)b * N_ * D_;
    // V staging source: thread t covers (d = v>>2, part = v&3), v = i*512+t
    const int vd0 = t >> 2, vpart = (t & 3) * 8;
    const u16* Vsrc = Vpt + (size_t)(b * D_) * N_ + vpart;

    // Q fragments: 8 heads x k=64, A-operand layout, persistent (64 VGPRs)
    short8 qfrag[8][2];
    {
        const u16* qb = Qp + ((size_t)(b * N_ + n0 + lane16) * D_ + quad * 8);
        #pragma unroll
        for (int h = 0; h < 8; ++h)
            #pragma unroll
            for (int dc = 0; dc < 2; ++dc)
                qfrag[h][dc] = *(const short8*)(qb + h * 64 + dc * 32);
    }

    float4v aacc[8][2];                // 8 heads x 2 owned d-tiles (64 regs)
    #pragma unroll
    for (int h = 0; h < 8; ++h)
        #pragma unroll
        for (int dt = 0; dt < 2; ++dt)
            aacc[h][dt] = (float4v){0.f, 0.f, 0.f, 0.f};

    ushort8 vreg[4];                   // V prefetch registers (16 VGPRs)
    const int nch = seg / 32;          // 32 chunks

    // ---- prologue: Kg(0), Vl(0), Kg(1); drain Kg(0); barrier ----
    #pragma unroll
    for (int i = 0; i < 4; ++i)
        gload_lds16(Kb + (size_t)(mbeg + w * 4 + i) * D_ + l * 8,
                    &Ks[0][w * 4 + i][0]);
    #pragma unroll
    for (int i = 0; i < 4; ++i)
        vreg[i] = *(const ushort8*)(Vsrc + (size_t)(i * 128 + vd0) * N_ + mbeg);
    #pragma unroll
    for (int i = 0; i < 4; ++i)
        gload_lds16(Kb + (size_t)(mbeg + 32 + w * 4 + i) * D_ + l * 8,
                    &Ks[1][w * 4 + i][0]);
    WAIT_VM(8);            // drain Kg(0); Vl(0)+Kg(1) stay in flight
    BARRIER;               // all waves' Kg(0) landed

    for (int c = 0; c < nch; ++c) {
        const int cur = c & 1;
        const int mc  = mbeg + c * 32;

        // ---- 1: drain own V-reg loads(c) ----
        if (c < nch - 1) { WAIT_VM(4); } else { WAIT_VM(0); }

        // ---- 2: commit V(c) to Vs ----
        #pragma unroll
        for (int i = 0; i < 4; ++i)
            *(ushort8*)&Vs[i * 128 + vd0][vpart] = vreg[i];

        // ---- 3: QK^T (8 heads, own 16-m half) ----
        float4v sacc[8];
        #pragma unroll
        for (int h = 0; h < 8; ++h) sacc[h] = (float4v){0.f, 0.f, 0.f, 0.f};
        __builtin_amdgcn_s_setprio(1);
        #pragma unroll
        for (int h = 0; h < 8; ++h)
            #pragma unroll
            for (int dc = 0; dc < 2; ++dc) {
                short8 kf = *(const short8*)
                    &Ks[cur][ms * 16 + lane16][h * 64 + dc * 32 + quad * 8];
                sacc[h] = __builtin_amdgcn_mfma_f32_16x16x32_bf16(
                    qfrag[h][dc], kf, sacc[h], 0, 0, 0);
            }
        __builtin_amdgcn_s_setprio(0);

        // ---- 4: register heads-softmax -> Ps ----
        #pragma unroll
        for (int r = 0; r < 4; ++r) {
            float p[8]; float sum = 0.f;
            #pragma unroll
            for (int h = 0; h < 8; ++h) {
                p[h] = __expf(sacc[h][r] * 0.125f);   // 1/sqrt(64)
                sum += p[h];
            }
            float inv = __builtin_amdgcn_rcpf(sum);
            #pragma unroll
            for (int h = 0; h < 8; ++h)
                Ps[ns][h][quad * 4 + r][ms * 16 + lane16] = f2bf_fast(p[h] * inv);
        }

        // ---- 5: prefetch V(c+1) into registers ----
        if (c + 1 < nch) {
            #pragma unroll
            for (int i = 0; i < 4; ++i)
                vreg[i] = *(const ushort8*)
                    (Vsrc + (size_t)(i * 128 + vd0) * N_ + mc + 32);
        }

        // ---- 6: Ps+Vs visible; VMEM prefetches stay in flight ----
        WAIT_LGKM0;
        BARRIER;

        // ---- 7: prefetch K(c+2) into the Ks buffer QK(c) just freed ----
        if (c + 2 < nch) {
            #pragma unroll
            for (int i = 0; i < 4; ++i)
                gload_lds16(Kb + (size_t)(mc + 64 + w * 4 + i) * D_ + l * 8,
                            &Ks[cur][w * 4 + i][0]);
        }

        // ---- 8: PV, full k=32; each wave owns d-tiles ms*2 + {0,1} ----
        __builtin_amdgcn_s_setprio(1);
        #pragma unroll
        for (int h = 0; h < 8; ++h) {
            short8 pf = *(const short8*)&Ps[ns][h][lane16][quad * 8];
            #pragma unroll
            for (int dt = 0; dt < 2; ++dt) {
                short8 vf = *(const short8*)
                    &Vs[h * 64 + (ms * 2 + dt) * 16 + lane16][quad * 8];
                aacc[h][dt] = __builtin_amdgcn_mfma_f32_16x16x32_bf16(
                    pf, vf, aacc[h][dt], 0, 0, 0);
            }
        }
        __builtin_amdgcn_s_setprio(0);

        // ---- 9: drain own Kg(c+1) before barrier -> QK(c+1) safe ----
        if (c < nch - 1) {
            if (c + 2 < nch) { WAIT_VM(8); } else { WAIT_VM(4); }
            WAIT_LGKM0;
            BARRIER;
        }
    }

    // ---- store partial A (bf16), own d-columns only ----
    #pragma unroll
    for (int h = 0; h < 8; ++h)
        #pragma unroll
        for (int dt = 0; dt < 2; ++dt)
            #pragma unroll
            for (int r = 0; r < 4; ++r) {
                const int n = n0 + quad * 4 + r;
                const int d = h * 64 + (ms * 2 + dt) * 16 + lane16;
                A[(size_t)(b * N_ + n) * D_ + d] = f2bf(aacc[h][dt][r]);
            }
}

// ---------------------------------------------------------------------------
extern "C" void kernel_launch(void* const* d_in, const int* in_sizes, int n_in,
                              void* d_out, int out_size, void* d_ws, size_t ws_size,
                              hipStream_t stream)
{
    const float* Q  = (const float*)d_in[0];
    const float* K  = (const float*)d_in[1];
    const float* V  = (const float*)d_in[2];
    const float* Wq = (const float*)d_in[3];
    const float* bq = (const float*)d_in[4];
    const float* Wo = (const float*)d_in[5];
    const float* bo = (const float*)d_in[6];
    float* out = (float*)d_out;
    u16*   ws  = (u16*)d_ws;

    const size_t NBD = (size_t)B_ * N_ * D_;   // 4,194,304

    // Single path (43.0 MB): Qp | Kp | Vpt | Pa | Pb | Wb
    u16* Qp  = ws;
    u16* Kp  = ws + NBD;
    u16* Vpt = ws + 2 * NBD;
    u16* Pa  = ws + 3 * NBD;
    u16* Pb  = ws + 4 * NBD;
    u16* Wb  = ws + 5 * NBD;

    wconv<<<dim3(128, 2), dim3(256), 0, stream>>>(Wq, Wo, Wb);

    proj1_mfma<<<dim3(768), dim3(256), 0, stream>>>(
        Q, K, V, Wb, bq, Qp);              // -> Qp, Kp, Vpt

    attn_mfma6<<<dim3(256), dim3(512), 0, stream>>>(Qp, Kp, Vpt, Pa);

    proj2_mfma<<<dim3(512), dim3(256), 0, stream>>>(
        Pa, Pb, Wb + (size_t)D_ * D_, bo, out);
}

// Round 7
// 224.489 us; speedup vs baseline: 1.0719x; 1.0719x over previous
//
#include <hip/hip_runtime.h>
#include <hip/hip_bf16.h>

// B,N,D,H = 4,2048,512,8 (DK=64). fp32 I/O; bf16 intermediates in ws.
// v10 = R5 structure (cvt4 + gload proj1 + attn v6 + proj2) with the
// attn-v6-proven counted-vmcnt single-barrier pipeline ported to BOTH
// projection GEMMs (old: 2 barriers + full vmcnt(0) drain per K-step):
//  proj1g: all-gload, TRIPLE-buffered As/Bs (48KB, 3 blocks/CU), steady
//          state VM(4)+1 barrier/K-step, gloads issued 2 steps ahead.
//  proj2p: A=P0+P1 reg-prefetch issued 1 step early (T14), B=W gload
//          double-buffered; VM(0) lands on loads a full MFMA+bar old.
//  proj1f: Path-B fallback, fp32 A reg-prefetch, same skeleton.
// attn = v6 + f2bf_fast Ps (101.9us R6-proven).
#define B_  4
#define N_  2048
#define D_  512
#define H_  8

typedef unsigned short u16;
typedef __attribute__((ext_vector_type(8))) unsigned short ushort8;
typedef __attribute__((ext_vector_type(4))) unsigned short us4;
typedef __attribute__((ext_vector_type(8))) short short8;
typedef __attribute__((ext_vector_type(4))) float float4v;

__device__ __forceinline__ float bf2f(u16 u) {
    union { unsigned int i; float f; } v;
    v.i = ((unsigned int)u) << 16;
    return v.f;
}
__device__ __forceinline__ u16 f2bf(float f) {          // RNE
    union { float f; unsigned int i; } v;
    v.f = f;
    unsigned int r = v.i + 0x7FFFu + ((v.i >> 16) & 1u);
    return (u16)(r >> 16);
}
__device__ __forceinline__ u16 f2bf_fast(float f) {     // round-half-up
    union { float f; unsigned int i; } v;
    v.f = f;
    return (u16)((v.i + 0x8000u) >> 16);
}

// async global->LDS, 16B/lane, dest = wave-uniform base + lane*16 (m104 rule)
__device__ __forceinline__ void gload_lds16(const void* g, void* l) {
    __builtin_amdgcn_global_load_lds(
        (const __attribute__((address_space(1))) unsigned int*)g,
        (__attribute__((address_space(3))) unsigned int*)l, 16, 0, 0);
}

#define WAIT_VM(N) do { \
    asm volatile("s_waitcnt vmcnt(" #N ")" ::: "memory"); \
    __builtin_amdgcn_sched_barrier(0); } while (0)
#define WAIT_LGKM0 do { \
    asm volatile("s_waitcnt lgkmcnt(0)" ::: "memory"); \
    __builtin_amdgcn_sched_barrier(0); } while (0)
#define BARRIER do { \
    __builtin_amdgcn_s_barrier(); \
    __builtin_amdgcn_sched_barrier(0); } while (0)

// ---------------------------------------------------------------------------
// wconv: Wq,Wo fp32 -> bf16, out = [Wqb | Wob]. grid (128, 2) x 256. Path B.
// ---------------------------------------------------------------------------
__global__ __launch_bounds__(256) void wconv(
    const float* __restrict__ Wq, const float* __restrict__ Wo,
    u16* __restrict__ out)
{
    const int idx = (blockIdx.x * 256 + threadIdx.x) * 8;
    const float* src = blockIdx.y ? Wo : Wq;
    u16* dst = out + (size_t)blockIdx.y * (D_ * D_) + idx;
    float4v a = *(const float4v*)(src + idx);
    float4v b = *(const float4v*)(src + idx + 4);
    ushort8 o;
    #pragma unroll
    for (int j = 0; j < 4; ++j) { o[j] = f2bf(a[j]); o[j + 4] = f2bf(b[j]); }
    *(ushort8*)dst = o;
}

// ---------------------------------------------------------------------------
// cvt4: Q,K,V fp32 -> bf16 slabs, + Wq/Wo -> Wb fused (y==3 blocks).
// grid (NBD/2048, 4) x 256. Path A.
// ---------------------------------------------------------------------------
__global__ __launch_bounds__(256) void cvt4(
    const float* __restrict__ Q, const float* __restrict__ K,
    const float* __restrict__ V, const float* __restrict__ Wq,
    const float* __restrict__ Wo, u16* __restrict__ out,
    u16* __restrict__ wb)
{
    const int y = blockIdx.y;
    if (y == 3) {                      // weight conversion: 2*D*D elems
        if (blockIdx.x >= 256) return; // 256 blocks * 2048 = 524,288
        const int idx = (blockIdx.x * 256 + threadIdx.x) * 8;
        const bool hi = idx >= D_ * D_;     // no straddle: 2048 | D*D
        const float* src = hi ? Wo : Wq;
        const int off = hi ? idx - D_ * D_ : idx;
        float4v a = *(const float4v*)(src + off);
        float4v b = *(const float4v*)(src + off + 4);
        ushort8 o;
        #pragma unroll
        for (int j = 0; j < 4; ++j) { o[j] = f2bf(a[j]); o[j + 4] = f2bf(b[j]); }
        *(ushort8*)(wb + idx) = o;
        return;
    }
    const size_t NBD = (size_t)B_ * N_ * D_;
    const float* src = (y == 0) ? Q : ((y == 1) ? K : V);
    u16* dst = out + (size_t)y * NBD;
    size_t idx = ((size_t)blockIdx.x * 256 + threadIdx.x) * 8;
    float4v a = *(const float4v*)(src + idx);
    float4v b = *(const float4v*)(src + idx + 4);
    ushort8 o;
    #pragma unroll
    for (int j = 0; j < 4; ++j) { o[j] = f2bf(a[j]); o[j + 4] = f2bf(b[j]); }
    *(ushort8*)(dst + idx) = o;
}

// ---------------------------------------------------------------------------
// shared epilogue for proj1 variants: bf16 out, z==2 -> transposed Vpt.
// ---------------------------------------------------------------------------
__device__ __forceinline__ void proj1_store(
    float4v (&acc)[4][4], const float* bias, u16* C0,
    int z, int m0, int e0, int wr, int wc, int lane16, int quad)
{
    float bj[4];
    #pragma unroll
    for (int j = 0; j < 4; ++j) bj[j] = bias[e0 + wc + j * 16 + lane16];

    if (z == 2) {   // transposed store: Vpt[b][e][n]
        u16* C = C0 + 2 * (size_t)B_ * N_ * D_;
        #pragma unroll
        for (int i = 0; i < 4; ++i) {
            int mrow = m0 + wr + i * 16 + quad * 4;
            int bb = mrow >> 11, nb = mrow & (N_ - 1);
            #pragma unroll
            for (int j = 0; j < 4; ++j) {
                int e = e0 + wc + j * 16 + lane16;
                us4 o;
                #pragma unroll
                for (int r = 0; r < 4; ++r) o[r] = f2bf(acc[i][j][r] + bj[j]);
                *(us4*)(C + (size_t)(bb * D_ + e) * N_ + nb) = o;
            }
        }
    } else {
        u16* C = C0 + (size_t)z * (size_t)B_ * N_ * D_;
        #pragma unroll
        for (int i = 0; i < 4; ++i)
            #pragma unroll
            for (int j = 0; j < 4; ++j) {
                int e = e0 + wc + j * 16 + lane16;
                #pragma unroll
                for (int r = 0; r < 4; ++r) {
                    int mrow = m0 + wr + i * 16 + quad * 4 + r;
                    C[(size_t)mrow * D_ + e] = f2bf(acc[i][j][r] + bj[j]);
                }
            }
    }
}

// ---------------------------------------------------------------------------
// proj1g (Path A): Xp[z] = Xb[z] @ Wq^T + bq, all inputs bf16, all staging
// via gload. TRIPLE-buffered As/Bs (48KB): per K-step (16 total):
//   VM(4) [drain stage(c); stage(c+1) stays in flight] ; BARRIER ;
//   ds_read frags(c) ; issue stage(c+2) -> buf[(c+2)%3] ; 16 MFMA.
// One barrier per K-step, no vmcnt(0) until the tail.
// grid 768 (3 blocks/CU), XCD swizzle: flat&7 = (z,m) low bits.
// ---------------------------------------------------------------------------
__global__ __launch_bounds__(256) void proj1g(
    const u16* __restrict__ Xb, const u16* __restrict__ Wb,
    const float* __restrict__ bias, u16* __restrict__ C0)
{
    __shared__ u16 As[3][128][32];
    __shared__ u16 Bs[3][128][32];

    const int t = threadIdx.x;
    const int flat = blockIdx.x;
    const int xcd = flat & 7, rr = flat >> 3;
    const int eb = rr & 3, g = rr >> 2;
    const int zm = xcd + 8 * g;          // 0 .. 191
    const int z  = zm >> 6;
    const int e0 = eb * 128;
    const int m0 = (zm & 63) * 128;

    const u16* X = Xb + (size_t)z * ((size_t)B_ * N_ * D_);
    const int w = t >> 6, l = t & 63;
    const int lane16 = l & 15, quad = l >> 4;
    const int wr = (w >> 1) * 64;
    const int wc = (w & 1) * 64;

    const int arow = l >> 2, acol = (l & 3) * 8;   // gload source lane map

    float4v acc[4][4];
    #pragma unroll
    for (int i = 0; i < 4; ++i)
        #pragma unroll
        for (int j = 0; j < 4; ++j)
            acc[i][j] = (float4v){0.f, 0.f, 0.f, 0.f};

    // stage(buf, k0): 2 A-gloads + 2 B-gloads per wave (4 vmem ops)
#define P1_STAGE(buf, k0) do { \
        _Pragma("unroll") \
        for (int i = 0; i < 2; ++i) { \
            int r0 = w * 32 + i * 16; \
            gload_lds16(X + (size_t)(m0 + r0 + arow) * 512 + (k0) + acol, \
                        &As[buf][r0][0]); \
        } \
        _Pragma("unroll") \
        for (int i = 0; i < 2; ++i) { \
            int r0 = w * 32 + i * 16; \
            gload_lds16(Wb + (size_t)(e0 + r0 + arow) * 512 + (k0) + acol, \
                        &Bs[buf][r0][0]); \
        } } while (0)

    P1_STAGE(0, 0);
    P1_STAGE(1, 32);

    #pragma unroll
    for (int c = 0; c < 16; ++c) {
        const int cur = c % 3;
        if (c < 15) { WAIT_VM(4); } else { WAIT_VM(0); }
        BARRIER;

        short8 af[4], bfr[4];
        #pragma unroll
        for (int i = 0; i < 4; ++i)
            af[i] = *(const short8*)&As[cur][wr + i * 16 + lane16][quad * 8];
        #pragma unroll
        for (int j = 0; j < 4; ++j)
            bfr[j] = *(const short8*)&Bs[cur][wc + j * 16 + lane16][quad * 8];

        if (c + 2 < 16) P1_STAGE((c + 2) % 3, (c + 2) * 32);

        __builtin_amdgcn_s_setprio(1);
        #pragma unroll
        for (int i = 0; i < 4; ++i)
            #pragma unroll
            for (int j = 0; j < 4; ++j)
                acc[i][j] = __builtin_amdgcn_mfma_f32_16x16x32_bf16(
                    af[i], bfr[j], acc[i][j], 0, 0, 0);
        __builtin_amdgcn_s_setprio(0);
    }
#undef P1_STAGE

    proj1_store(acc, bias, C0, z, m0, e0, wr, wc, lane16, quad);
}

// ---------------------------------------------------------------------------
// proj1f (Path B): X fp32, A staged via reg-prefetch (issued 1 K-step early,
// T14), B via gload double-buffered. Per K-step: VM(0) [loads are a full
// MFMA+barrier old] ; ds_write As[cur] ; LGKM0 ; BARRIER ; ds_read frags ;
// issue loads(c+1) ; 16 MFMA. One barrier per K-step.
// ---------------------------------------------------------------------------
__global__ __launch_bounds__(256) void proj1f(
    const float* __restrict__ X0, const float* __restrict__ X1,
    const float* __restrict__ X2, const u16* __restrict__ Wb,
    const float* __restrict__ bias, u16* __restrict__ C0)
{
    __shared__ u16 As[2][128][32];
    __shared__ u16 Bs[2][128][32];

    const int t = threadIdx.x;
    const int flat = blockIdx.x;
    const int xcd = flat & 7, rr = flat >> 3;
    const int eb = rr & 3, g = rr >> 2;
    const int zm = xcd + 8 * g;
    const int z  = zm >> 6;
    const int e0 = eb * 128;
    const int m0 = (zm & 63) * 128;

    const float* X = (z == 0) ? X0 : ((z == 1) ? X1 : X2);
    const int w = t >> 6, l = t & 63;
    const int lane16 = l & 15, quad = l >> 4;
    const int wr = (w >> 1) * 64;
    const int wc = (w & 1) * 64;
    const int arow = l >> 2, acol = (l & 3) * 8;

    const int xrow = t >> 2, xc8 = (t & 3) * 8;    // A reg-load lane map

    float4v acc[4][4];
    #pragma unroll
    for (int i = 0; i < 4; ++i)
        #pragma unroll
        for (int j = 0; j < 4; ++j)
            acc[i][j] = (float4v){0.f, 0.f, 0.f, 0.f};

    float4v xr[2][2][2];   // [i][half][vec4] - 2 rows-of-512 per thread

#define P1F_LOADA(k0) do { \
        _Pragma("unroll") \
        for (int i = 0; i < 2; ++i) { \
            const float* xp = X + (size_t)(m0 + xrow + i * 64) * 512 + (k0) + xc8; \
            xr[i][0][0] = *(const float4v*)xp; \
            xr[i][0][1] = *(const float4v*)(xp + 4); \
        } } while (0)
    // note: [i][0][*] used; second half slot kept for layout clarity

#define P1F_STAGEB(buf, k0) do { \
        _Pragma("unroll") \
        for (int i = 0; i < 2; ++i) { \
            int r0 = w * 32 + i * 16; \
            gload_lds16(Wb + (size_t)(e0 + r0 + arow) * 512 + (k0) + acol, \
                        &Bs[buf][r0][0]); \
        } } while (0)

    P1F_LOADA(0);
    P1F_STAGEB(0, 0);

    #pragma unroll
    for (int c = 0; c < 16; ++c) {
        const int cur = c & 1;
        WAIT_VM(0);

        #pragma unroll
        for (int i = 0; i < 2; ++i) {
            ushort8 o;
            #pragma unroll
            for (int j = 0; j < 4; ++j) {
                o[j]     = f2bf_fast(xr[i][0][0][j]);
                o[j + 4] = f2bf_fast(xr[i][0][1][j]);
            }
            *(ushort8*)&As[cur][xrow + i * 64][xc8] = o;
        }
        WAIT_LGKM0;
        BARRIER;

        short8 af[4], bfr[4];
        #pragma unroll
        for (int i = 0; i < 4; ++i)
            af[i] = *(const short8*)&As[cur][wr + i * 16 + lane16][quad * 8];
        #pragma unroll
        for (int j = 0; j < 4; ++j)
            bfr[j] = *(const short8*)&Bs[cur][wc + j * 16 + lane16][quad * 8];

        if (c + 1 < 16) {
            P1F_LOADA((c + 1) * 32);
            P1F_STAGEB(cur ^ 1, (c + 1) * 32);
        }

        __builtin_amdgcn_s_setprio(1);
        #pragma unroll
        for (int i = 0; i < 4; ++i)
            #pragma unroll
            for (int j = 0; j < 4; ++j)
                acc[i][j] = __builtin_amdgcn_mfma_f32_16x16x32_bf16(
                    af[i], bfr[j], acc[i][j], 0, 0, 0);
        __builtin_amdgcn_s_setprio(0);
    }
#undef P1F_LOADA
#undef P1F_STAGEB

    proj1_store(acc, bias, C0, z, m0, e0, wr, wc, lane16, quad);
}

// ---------------------------------------------------------------------------
// proj2p: out[8192,512] = (P0+P1) @ Wo^T + bo, fp32 out. 128x64 tile,
// 512 blocks = 2 blocks/CU. A = P0+P1 reg-prefetch (T14, 1 step early),
// B = W gload double-buffered. One barrier per K-step.
// ---------------------------------------------------------------------------
__global__ __launch_bounds__(256) void proj2p(
    const u16* __restrict__ P0, const u16* __restrict__ P1,
    const u16* __restrict__ Wv, const float* __restrict__ bias,
    float* __restrict__ C)
{
    __shared__ u16 As[2][128][32];
    __shared__ u16 Bs[2][64][32];

    const int t = threadIdx.x;
    const int flat = blockIdx.x;
    const int xcd = flat & 7, rr = flat >> 3;
    const int eb = rr & 7, g = rr >> 3;
    const int m0 = (xcd + 8 * g) * 128;
    const int e0 = eb * 64;

    const int w = t >> 6, l = t & 63;
    const int lane16 = l & 15, quad = l >> 4;
    const int wr = (w >> 1) * 64;
    const int wc = (w & 1) * 32;
    const int arow = l >> 2, acol = (l & 3) * 8;
    const int xrow = t >> 2, xc8 = (t & 3) * 8;

    float4v acc[4][2];
    #pragma unroll
    for (int i = 0; i < 4; ++i)
        #pragma unroll
        for (int j = 0; j < 2; ++j)
            acc[i][j] = (float4v){0.f, 0.f, 0.f, 0.f};

    ushort8 pa[2], pb[2];

#define P2_LOADP(k0) do { \
        _Pragma("unroll") \
        for (int i = 0; i < 2; ++i) { \
            size_t gi = (size_t)(m0 + xrow + i * 64) * 512 + (k0) + xc8; \
            pa[i] = *(const ushort8*)(P0 + gi); \
            pb[i] = *(const ushort8*)(P1 + gi); \
        } } while (0)

    P2_LOADP(0);
    gload_lds16(Wv + (size_t)(e0 + w * 16 + arow) * 512 + 0 + acol, &Bs[0][w * 16][0]);

    #pragma unroll
    for (int c = 0; c < 16; ++c) {
        const int cur = c & 1;
        WAIT_VM(0);

        #pragma unroll
        for (int i = 0; i < 2; ++i) {
            ushort8 o;
            #pragma unroll
            for (int j = 0; j < 8; ++j)
                o[j] = f2bf(bf2f(pa[i][j]) + bf2f(pb[i][j]));
            *(ushort8*)&As[cur][xrow + i * 64][xc8] = o;
        }
        WAIT_LGKM0;
        BARRIER;

        short8 af[4], bfr[2];
        #pragma unroll
        for (int i = 0; i < 4; ++i)
            af[i] = *(const short8*)&As[cur][wr + i * 16 + lane16][quad * 8];
        #pragma unroll
        for (int j = 0; j < 2; ++j)
            bfr[j] = *(const short8*)&Bs[cur][wc + j * 16 + lane16][quad * 8];

        if (c + 1 < 16) {
            P2_LOADP((c + 1) * 32);
            gload_lds16(Wv + (size_t)(e0 + w * 16 + arow) * 512 + (c + 1) * 32 + acol,
                        &Bs[cur ^ 1][w * 16][0]);
        }

        __builtin_amdgcn_s_setprio(1);
        #pragma unroll
        for (int i = 0; i < 4; ++i)
            #pragma unroll
            for (int j = 0; j < 2; ++j)
                acc[i][j] = __builtin_amdgcn_mfma_f32_16x16x32_bf16(
                    af[i], bfr[j], acc[i][j], 0, 0, 0);
        __builtin_amdgcn_s_setprio(0);
    }
#undef P2_LOADP

    float bj[2];
    #pragma unroll
    for (int j = 0; j < 2; ++j) bj[j] = bias[e0 + wc + j * 16 + lane16];

    #pragma unroll
    for (int i = 0; i < 4; ++i)
        #pragma unroll
        for (int j = 0; j < 2; ++j) {
            int e = e0 + wc + j * 16 + lane16;
            #pragma unroll
            for (int r = 0; r < 4; ++r) {
                int mrow = m0 + wr + i * 16 + quad * 4 + r;
                C[(size_t)mrow * D_ + e] = acc[i][j][r] + bj[j];
            }
        }
}

// ---------------------------------------------------------------------------
// attn v6 (101.9us R6-proven): 512 thr = 8 waves (ns owns 16 n-rows, ms
// splits the 32-m chunk). Counted-vmcnt pipeline; Vs/Ps stride 36.
// ---------------------------------------------------------------------------
__global__ __launch_bounds__(512, 2) void attn_mfma6(
    const u16* __restrict__ Qp, const u16* __restrict__ Kp,
    const u16* __restrict__ Vpt, u16* __restrict__ A0)
{
    __shared__ u16 Ks[2][32][520];     // 66,560 B double-buffered K
    __shared__ u16 Vs[512][36];        // 36,864 B (stride-36: clean banks)
    __shared__ u16 Ps[4][8][16][36];   // 36,864 B pair-shared P per n-tile

    const int t = threadIdx.x;
    const int w = t >> 6, l = t & 63;
    const int lane16 = l & 15, quad = l >> 4;
    const int ns = w >> 1, ms = w & 1;

    const int flat = blockIdx.x;
    const int xcd  = flat & 7;
    const int b = xcd >> 1;            // (b, z) pinned to one XCD
    const int z = xcd & 1;
    const int n0 = (flat >> 3) * 64 + ns * 16;   // this wave-pair's 16 rows
    const int seg  = N_ / 2;
    const int mbeg = z * seg;
    u16* A = A0 + (size_t)z * ((size_t)B_ * N_ * D_);

    const u16* Kb = Kp + (size_t)b * N_ * D_;
    const int vd0 = t >> 2, vpart = (t & 3) * 8;
    const u16* Vsrc = Vpt + (size_t)(b * D_) * N_ + vpart;

    // Q fragments: 8 heads x k=64, A-operand layout, persistent (64 VGPRs)
    short8 qfrag[8][2];
    {
        const u16* qb = Qp + ((size_t)(b * N_ + n0 + lane16) * D_ + quad * 8);
        #pragma unroll
        for (int h = 0; h < 8; ++h)
            #pragma unroll
            for (int dc = 0; dc < 2; ++dc)
                qfrag[h][dc] = *(const short8*)(qb + h * 64 + dc * 32);
    }

    float4v aacc[8][2];                // 8 heads x 2 owned d-tiles (64 regs)
    #pragma unroll
    for (int h = 0; h < 8; ++h)
        #pragma unroll
        for (int dt = 0; dt < 2; ++dt)
            aacc[h][dt] = (float4v){0.f, 0.f, 0.f, 0.f};

    ushort8 vreg[4];                   // V prefetch registers (16 VGPRs)
    const int nch = seg / 32;          // 32 chunks

    // ---- prologue: Kg(0), Vl(0), Kg(1); drain Kg(0); barrier ----
    #pragma unroll
    for (int i = 0; i < 4; ++i)
        gload_lds16(Kb + (size_t)(mbeg + w * 4 + i) * D_ + l * 8,
                    &Ks[0][w * 4 + i][0]);
    #pragma unroll
    for (int i = 0; i < 4; ++i)
        vreg[i] = *(const ushort8*)(Vsrc + (size_t)(i * 128 + vd0) * N_ + mbeg);
    #pragma unroll
    for (int i = 0; i < 4; ++i)
        gload_lds16(Kb + (size_t)(mbeg + 32 + w * 4 + i) * D_ + l * 8,
                    &Ks[1][w * 4 + i][0]);
    WAIT_VM(8);            // drain Kg(0); Vl(0)+Kg(1) stay in flight
    BARRIER;               // all waves' Kg(0) landed

    for (int c = 0; c < nch; ++c) {
        const int cur = c & 1;
        const int mc  = mbeg + c * 32;

        // ---- 1: drain own V-reg loads(c) ----
        if (c < nch - 1) { WAIT_VM(4); } else { WAIT_VM(0); }

        // ---- 2: commit V(c) to Vs ----
        #pragma unroll
        for (int i = 0; i < 4; ++i)
            *(ushort8*)&Vs[i * 128 + vd0][vpart] = vreg[i];

        // ---- 3: QK^T (8 heads, own 16-m half) ----
        float4v sacc[8];
        #pragma unroll
        for (int h = 0; h < 8; ++h) sacc[h] = (float4v){0.f, 0.f, 0.f, 0.f};
        __builtin_amdgcn_s_setprio(1);
        #pragma unroll
        for (int h = 0; h < 8; ++h)
            #pragma unroll
            for (int dc = 0; dc < 2; ++dc) {
                short8 kf = *(const short8*)
                    &Ks[cur][ms * 16 + lane16][h * 64 + dc * 32 + quad * 8];
                sacc[h] = __builtin_amdgcn_mfma_f32_16x16x32_bf16(
                    qfrag[h][dc], kf, sacc[h], 0, 0, 0);
            }
        __builtin_amdgcn_s_setprio(0);

        // ---- 4: register heads-softmax -> Ps ----
        #pragma unroll
        for (int r = 0; r < 4; ++r) {
            float p[8]; float sum = 0.f;
            #pragma unroll
            for (int h = 0; h < 8; ++h) {
                p[h] = __expf(sacc[h][r] * 0.125f);   // 1/sqrt(64)
                sum += p[h];
            }
            float inv = __builtin_amdgcn_rcpf(sum);
            #pragma unroll
            for (int h = 0; h < 8; ++h)
                Ps[ns][h][quad * 4 + r][ms * 16 + lane16] = f2bf_fast(p[h] * inv);
        }

        // ---- 5: prefetch V(c+1) into registers ----
        if (c + 1 < nch) {
            #pragma unroll
            for (int i = 0; i < 4; ++i)
                vreg[i] = *(const ushort8*)
                    (Vsrc + (size_t)(i * 128 + vd0) * N_ + mc + 32);
        }

        // ---- 6: Ps+Vs visible; VMEM prefetches stay in flight ----
        WAIT_LGKM0;
        BARRIER;

        // ---- 7: prefetch K(c+2) into the Ks buffer QK(c) just freed ----
        if (c + 2 < nch) {
            #pragma unroll
            for (int i = 0; i < 4; ++i)
                gload_lds16(Kb + (size_t)(mc + 64 + w * 4 + i) * D_ + l * 8,
                            &Ks[cur][w * 4 + i][0]);
        }

        // ---- 8: PV, full k=32; each wave owns d-tiles ms*2 + {0,1} ----
        __builtin_amdgcn_s_setprio(1);
        #pragma unroll
        for (int h = 0; h < 8; ++h) {
            short8 pf = *(const short8*)&Ps[ns][h][lane16][quad * 8];
            #pragma unroll
            for (int dt = 0; dt < 2; ++dt) {
                short8 vf = *(const short8*)
                    &Vs[h * 64 + (ms * 2 + dt) * 16 + lane16][quad * 8];
                aacc[h][dt] = __builtin_amdgcn_mfma_f32_16x16x32_bf16(
                    pf, vf, aacc[h][dt], 0, 0, 0);
            }
        }
        __builtin_amdgcn_s_setprio(0);

        // ---- 9: drain own Kg(c+1) before barrier -> QK(c+1) safe ----
        if (c < nch - 1) {
            if (c + 2 < nch) { WAIT_VM(8); } else { WAIT_VM(4); }
            WAIT_LGKM0;
            BARRIER;
        }
    }

    // ---- store partial A (bf16), own d-columns only ----
    #pragma unroll
    for (int h = 0; h < 8; ++h)
        #pragma unroll
        for (int dt = 0; dt < 2; ++dt)
            #pragma unroll
            for (int r = 0; r < 4; ++r) {
                const int n = n0 + quad * 4 + r;
                const int d = h * 64 + (ms * 2 + dt) * 16 + lane16;
                A[(size_t)(b * N_ + n) * D_ + d] = f2bf(aacc[h][dt][r]);
            }
}

// ---------------------------------------------------------------------------
extern "C" void kernel_launch(void* const* d_in, const int* in_sizes, int n_in,
                              void* d_out, int out_size, void* d_ws, size_t ws_size,
                              hipStream_t stream)
{
    const float* Q  = (const float*)d_in[0];
    const float* K  = (const float*)d_in[1];
    const float* V  = (const float*)d_in[2];
    const float* Wq = (const float*)d_in[3];
    const float* bq = (const float*)d_in[4];
    const float* Wo = (const float*)d_in[5];
    const float* bo = (const float*)d_in[6];
    float* out = (float*)d_out;
    u16*   ws  = (u16*)d_ws;

    const size_t NBD = (size_t)B_ * N_ * D_;   // 4,194,304

    const size_t need6 = (6 * NBD + 2 * (size_t)D_ * D_) * sizeof(u16); // 51.4 MB

    if (ws_size >= need6) {
        // Path A: bf16-ify inputs once; proj1 all-gload pipelined.
        // S0=Qb->Pa, S1=Kb->Pb, S2=Vb, S3=Qp, S4=Kp, S5=Vpt, then Wb.
        u16* S0 = ws;
        u16* S1 = ws + NBD;
        u16* S3 = ws + 3 * NBD;
        u16* Wb = ws + 6 * NBD;            // [Wqb | Wob]

        cvt4<<<dim3((unsigned)(NBD / 2048), 4), dim3(256), 0, stream>>>(
            Q, K, V, Wq, Wo, S0, Wb);

        proj1g<<<dim3(768), dim3(256), 0, stream>>>(S0, Wb, bq, S3);

        attn_mfma6<<<dim3(256), dim3(512), 0, stream>>>(
            S3, S3 + NBD, S3 + 2 * NBD, S0);   // partials -> S0, S1

        proj2p<<<dim3(512), dim3(256), 0, stream>>>(
            S0, S1, Wb + (size_t)D_ * D_, bo, out);
    } else {
        // Path B (43.0 MB): fp32-X reg-prefetch staging in proj1.
        u16* Qp  = ws;
        u16* Kp  = ws + NBD;
        u16* Vpt = ws + 2 * NBD;
        u16* Pa  = ws + 3 * NBD;
        u16* Pb  = ws + 4 * NBD;
        u16* Wb  = ws + 5 * NBD;

        wconv<<<dim3(128, 2), dim3(256), 0, stream>>>(Wq, Wo, Wb);

        proj1f<<<dim3(768), dim3(256), 0, stream>>>(Q, K, V, Wb, bq, Qp);

        attn_mfma6<<<dim3(256), dim3(512), 0, stream>>>(Qp, Kp, Vpt, Pa);

        proj2p<<<dim3(512), dim3(256), 0, stream>>>(
            Pa, Pb, Wb + (size_t)D_ * D_, bo, out);
    }
}

// Round 8
// 224.220 us; speedup vs baseline: 1.0732x; 1.0012x over previous
//
#include <hip/hip_runtime.h>
#include <hip/hip_bf16.h>

// B,N,D,H = 4,2048,512,8 (DK=64). fp32 I/O; bf16 intermediates in ws.
// v11 = v10 (cvt4 + proj1g + proj2p pipelined GEMMs) with attn v8:
//  - batched fragment loads: QK loads 8 kf frags to regs per 4-head group
//    before its 8 MFMAs; PV loads 4 pf + 8 vf (12 reads in flight) per
//    group. Raises outstanding ds_reads ~4x per wave (was ~2-3, VGPR=112
//    proved no hoisting) -> cuts exposed ~120cy LDS latency at 2 waves/SIMD.
//  - QK moved BEFORE the V-drain+commit (QK needs only Ks): V reg-loads get
//    ~400 more cyc to land; chunk starts computing immediately after BAR2.
//  - softmax sum as explicit tree.
#define B_  4
#define N_  2048
#define D_  512
#define H_  8

typedef unsigned short u16;
typedef __attribute__((ext_vector_type(8))) unsigned short ushort8;
typedef __attribute__((ext_vector_type(4))) unsigned short us4;
typedef __attribute__((ext_vector_type(8))) short short8;
typedef __attribute__((ext_vector_type(4))) float float4v;

__device__ __forceinline__ float bf2f(u16 u) {
    union { unsigned int i; float f; } v;
    v.i = ((unsigned int)u) << 16;
    return v.f;
}
__device__ __forceinline__ u16 f2bf(float f) {          // RNE
    union { float f; unsigned int i; } v;
    v.f = f;
    unsigned int r = v.i + 0x7FFFu + ((v.i >> 16) & 1u);
    return (u16)(r >> 16);
}
__device__ __forceinline__ u16 f2bf_fast(float f) {     // round-half-up
    union { float f; unsigned int i; } v;
    v.f = f;
    return (u16)((v.i + 0x8000u) >> 16);
}

// async global->LDS, 16B/lane, dest = wave-uniform base + lane*16 (m104 rule)
__device__ __forceinline__ void gload_lds16(const void* g, void* l) {
    __builtin_amdgcn_global_load_lds(
        (const __attribute__((address_space(1))) unsigned int*)g,
        (__attribute__((address_space(3))) unsigned int*)l, 16, 0, 0);
}

#define WAIT_VM(N) do { \
    asm volatile("s_waitcnt vmcnt(" #N ")" ::: "memory"); \
    __builtin_amdgcn_sched_barrier(0); } while (0)
#define WAIT_LGKM0 do { \
    asm volatile("s_waitcnt lgkmcnt(0)" ::: "memory"); \
    __builtin_amdgcn_sched_barrier(0); } while (0)
#define BARRIER do { \
    __builtin_amdgcn_s_barrier(); \
    __builtin_amdgcn_sched_barrier(0); } while (0)

// ---------------------------------------------------------------------------
// wconv: Wq,Wo fp32 -> bf16, out = [Wqb | Wob]. grid (128, 2) x 256. Path B.
// ---------------------------------------------------------------------------
__global__ __launch_bounds__(256) void wconv(
    const float* __restrict__ Wq, const float* __restrict__ Wo,
    u16* __restrict__ out)
{
    const int idx = (blockIdx.x * 256 + threadIdx.x) * 8;
    const float* src = blockIdx.y ? Wo : Wq;
    u16* dst = out + (size_t)blockIdx.y * (D_ * D_) + idx;
    float4v a = *(const float4v*)(src + idx);
    float4v b = *(const float4v*)(src + idx + 4);
    ushort8 o;
    #pragma unroll
    for (int j = 0; j < 4; ++j) { o[j] = f2bf(a[j]); o[j + 4] = f2bf(b[j]); }
    *(ushort8*)dst = o;
}

// ---------------------------------------------------------------------------
// cvt4: Q,K,V fp32 -> bf16 slabs, + Wq/Wo -> Wb fused (y==3 blocks).
// grid (NBD/2048, 4) x 256. Path A.
// ---------------------------------------------------------------------------
__global__ __launch_bounds__(256) void cvt4(
    const float* __restrict__ Q, const float* __restrict__ K,
    const float* __restrict__ V, const float* __restrict__ Wq,
    const float* __restrict__ Wo, u16* __restrict__ out,
    u16* __restrict__ wb)
{
    const int y = blockIdx.y;
    if (y == 3) {                      // weight conversion: 2*D*D elems
        if (blockIdx.x >= 256) return; // 256 blocks * 2048 = 524,288
        const int idx = (blockIdx.x * 256 + threadIdx.x) * 8;
        const bool hi = idx >= D_ * D_;     // no straddle: 2048 | D*D
        const float* src = hi ? Wo : Wq;
        const int off = hi ? idx - D_ * D_ : idx;
        float4v a = *(const float4v*)(src + off);
        float4v b = *(const float4v*)(src + off + 4);
        ushort8 o;
        #pragma unroll
        for (int j = 0; j < 4; ++j) { o[j] = f2bf(a[j]); o[j + 4] = f2bf(b[j]); }
        *(ushort8*)(wb + idx) = o;
        return;
    }
    const size_t NBD = (size_t)B_ * N_ * D_;
    const float* src = (y == 0) ? Q : ((y == 1) ? K : V);
    u16* dst = out + (size_t)y * NBD;
    size_t idx = ((size_t)blockIdx.x * 256 + threadIdx.x) * 8;
    float4v a = *(const float4v*)(src + idx);
    float4v b = *(const float4v*)(src + idx + 4);
    ushort8 o;
    #pragma unroll
    for (int j = 0; j < 4; ++j) { o[j] = f2bf(a[j]); o[j + 4] = f2bf(b[j]); }
    *(ushort8*)(dst + idx) = o;
}

// ---------------------------------------------------------------------------
// shared epilogue for proj1 variants: bf16 out, z==2 -> transposed Vpt.
// ---------------------------------------------------------------------------
__device__ __forceinline__ void proj1_store(
    float4v (&acc)[4][4], const float* bias, u16* C0,
    int z, int m0, int e0, int wr, int wc, int lane16, int quad)
{
    float bj[4];
    #pragma unroll
    for (int j = 0; j < 4; ++j) bj[j] = bias[e0 + wc + j * 16 + lane16];

    if (z == 2) {   // transposed store: Vpt[b][e][n]
        u16* C = C0 + 2 * (size_t)B_ * N_ * D_;
        #pragma unroll
        for (int i = 0; i < 4; ++i) {
            int mrow = m0 + wr + i * 16 + quad * 4;
            int bb = mrow >> 11, nb = mrow & (N_ - 1);
            #pragma unroll
            for (int j = 0; j < 4; ++j) {
                int e = e0 + wc + j * 16 + lane16;
                us4 o;
                #pragma unroll
                for (int r = 0; r < 4; ++r) o[r] = f2bf(acc[i][j][r] + bj[j]);
                *(us4*)(C + (size_t)(bb * D_ + e) * N_ + nb) = o;
            }
        }
    } else {
        u16* C = C0 + (size_t)z * (size_t)B_ * N_ * D_;
        #pragma unroll
        for (int i = 0; i < 4; ++i)
            #pragma unroll
            for (int j = 0; j < 4; ++j) {
                int e = e0 + wc + j * 16 + lane16;
                #pragma unroll
                for (int r = 0; r < 4; ++r) {
                    int mrow = m0 + wr + i * 16 + quad * 4 + r;
                    C[(size_t)mrow * D_ + e] = f2bf(acc[i][j][r] + bj[j]);
                }
            }
    }
}

// ---------------------------------------------------------------------------
// proj1g (Path A): Xp[z] = Xb[z] @ Wq^T + bq, all inputs bf16, all staging
// via gload. TRIPLE-buffered As/Bs (48KB): per K-step (16 total):
//   VM(4) [drain stage(c); stage(c+1) stays in flight] ; BARRIER ;
//   ds_read frags(c) ; issue stage(c+2) -> buf[(c+2)%3] ; 16 MFMA.
// One barrier per K-step, no vmcnt(0) until the tail.
// grid 768 (3 blocks/CU), XCD swizzle: flat&7 = (z,m) low bits.
// ---------------------------------------------------------------------------
__global__ __launch_bounds__(256) void proj1g(
    const u16* __restrict__ Xb, const u16* __restrict__ Wb,
    const float* __restrict__ bias, u16* __restrict__ C0)
{
    __shared__ u16 As[3][128][32];
    __shared__ u16 Bs[3][128][32];

    const int t = threadIdx.x;
    const int flat = blockIdx.x;
    const int xcd = flat & 7, rr = flat >> 3;
    const int eb = rr & 3, g = rr >> 2;
    const int zm = xcd + 8 * g;          // 0 .. 191
    const int z  = zm >> 6;
    const int e0 = eb * 128;
    const int m0 = (zm & 63) * 128;

    const u16* X = Xb + (size_t)z * ((size_t)B_ * N_ * D_);
    const int w = t >> 6, l = t & 63;
    const int lane16 = l & 15, quad = l >> 4;
    const int wr = (w >> 1) * 64;
    const int wc = (w & 1) * 64;

    const int arow = l >> 2, acol = (l & 3) * 8;   // gload source lane map

    float4v acc[4][4];
    #pragma unroll
    for (int i = 0; i < 4; ++i)
        #pragma unroll
        for (int j = 0; j < 4; ++j)
            acc[i][j] = (float4v){0.f, 0.f, 0.f, 0.f};

    // stage(buf, k0): 2 A-gloads + 2 B-gloads per wave (4 vmem ops)
#define P1_STAGE(buf, k0) do { \
        _Pragma("unroll") \
        for (int i = 0; i < 2; ++i) { \
            int r0 = w * 32 + i * 16; \
            gload_lds16(X + (size_t)(m0 + r0 + arow) * 512 + (k0) + acol, \
                        &As[buf][r0][0]); \
        } \
        _Pragma("unroll") \
        for (int i = 0; i < 2; ++i) { \
            int r0 = w * 32 + i * 16; \
            gload_lds16(Wb + (size_t)(e0 + r0 + arow) * 512 + (k0) + acol, \
                        &Bs[buf][r0][0]); \
        } } while (0)

    P1_STAGE(0, 0);
    P1_STAGE(1, 32);

    #pragma unroll
    for (int c = 0; c < 16; ++c) {
        const int cur = c % 3;
        if (c < 15) { WAIT_VM(4); } else { WAIT_VM(0); }
        BARRIER;

        short8 af[4], bfr[4];
        #pragma unroll
        for (int i = 0; i < 4; ++i)
            af[i] = *(const short8*)&As[cur][wr + i * 16 + lane16][quad * 8];
        #pragma unroll
        for (int j = 0; j < 4; ++j)
            bfr[j] = *(const short8*)&Bs[cur][wc + j * 16 + lane16][quad * 8];

        if (c + 2 < 16) P1_STAGE((c + 2) % 3, (c + 2) * 32);

        __builtin_amdgcn_s_setprio(1);
        #pragma unroll
        for (int i = 0; i < 4; ++i)
            #pragma unroll
            for (int j = 0; j < 4; ++j)
                acc[i][j] = __builtin_amdgcn_mfma_f32_16x16x32_bf16(
                    af[i], bfr[j], acc[i][j], 0, 0, 0);
        __builtin_amdgcn_s_setprio(0);
    }
#undef P1_STAGE

    proj1_store(acc, bias, C0, z, m0, e0, wr, wc, lane16, quad);
}

// ---------------------------------------------------------------------------
// proj1f (Path B): X fp32, A staged via reg-prefetch (issued 1 K-step early,
// T14), B via gload double-buffered. One barrier per K-step.
// ---------------------------------------------------------------------------
__global__ __launch_bounds__(256) void proj1f(
    const float* __restrict__ X0, const float* __restrict__ X1,
    const float* __restrict__ X2, const u16* __restrict__ Wb,
    const float* __restrict__ bias, u16* __restrict__ C0)
{
    __shared__ u16 As[2][128][32];
    __shared__ u16 Bs[2][128][32];

    const int t = threadIdx.x;
    const int flat = blockIdx.x;
    const int xcd = flat & 7, rr = flat >> 3;
    const int eb = rr & 3, g = rr >> 2;
    const int zm = xcd + 8 * g;
    const int z  = zm >> 6;
    const int e0 = eb * 128;
    const int m0 = (zm & 63) * 128;

    const float* X = (z == 0) ? X0 : ((z == 1) ? X1 : X2);
    const int w = t >> 6, l = t & 63;
    const int lane16 = l & 15, quad = l >> 4;
    const int wr = (w >> 1) * 64;
    const int wc = (w & 1) * 64;
    const int arow = l >> 2, acol = (l & 3) * 8;

    const int xrow = t >> 2, xc8 = (t & 3) * 8;    // A reg-load lane map

    float4v acc[4][4];
    #pragma unroll
    for (int i = 0; i < 4; ++i)
        #pragma unroll
        for (int j = 0; j < 4; ++j)
            acc[i][j] = (float4v){0.f, 0.f, 0.f, 0.f};

    float4v xr[2][2][2];   // [i][half][vec4] - 2 rows-of-512 per thread

#define P1F_LOADA(k0) do { \
        _Pragma("unroll") \
        for (int i = 0; i < 2; ++i) { \
            const float* xp = X + (size_t)(m0 + xrow + i * 64) * 512 + (k0) + xc8; \
            xr[i][0][0] = *(const float4v*)xp; \
            xr[i][0][1] = *(const float4v*)(xp + 4); \
        } } while (0)

#define P1F_STAGEB(buf, k0) do { \
        _Pragma("unroll") \
        for (int i = 0; i < 2; ++i) { \
            int r0 = w * 32 + i * 16; \
            gload_lds16(Wb + (size_t)(e0 + r0 + arow) * 512 + (k0) + acol, \
                        &Bs[buf][r0][0]); \
        } } while (0)

    P1F_LOADA(0);
    P1F_STAGEB(0, 0);

    #pragma unroll
    for (int c = 0; c < 16; ++c) {
        const int cur = c & 1;
        WAIT_VM(0);

        #pragma unroll
        for (int i = 0; i < 2; ++i) {
            ushort8 o;
            #pragma unroll
            for (int j = 0; j < 4; ++j) {
                o[j]     = f2bf_fast(xr[i][0][0][j]);
                o[j + 4] = f2bf_fast(xr[i][0][1][j]);
            }
            *(ushort8*)&As[cur][xrow + i * 64][xc8] = o;
        }
        WAIT_LGKM0;
        BARRIER;

        short8 af[4], bfr[4];
        #pragma unroll
        for (int i = 0; i < 4; ++i)
            af[i] = *(const short8*)&As[cur][wr + i * 16 + lane16][quad * 8];
        #pragma unroll
        for (int j = 0; j < 4; ++j)
            bfr[j] = *(const short8*)&Bs[cur][wc + j * 16 + lane16][quad * 8];

        if (c + 1 < 16) {
            P1F_LOADA((c + 1) * 32);
            P1F_STAGEB(cur ^ 1, (c + 1) * 32);
        }

        __builtin_amdgcn_s_setprio(1);
        #pragma unroll
        for (int i = 0; i < 4; ++i)
            #pragma unroll
            for (int j = 0; j < 4; ++j)
                acc[i][j] = __builtin_amdgcn_mfma_f32_16x16x32_bf16(
                    af[i], bfr[j], acc[i][j], 0, 0, 0);
        __builtin_amdgcn_s_setprio(0);
    }
#undef P1F_LOADA
#undef P1F_STAGEB

    proj1_store(acc, bias, C0, z, m0, e0, wr, wc, lane16, quad);
}

// ---------------------------------------------------------------------------
// proj2p: out[8192,512] = (P0+P1) @ Wo^T + bo, fp32 out. 128x64 tile,
// 512 blocks = 2 blocks/CU. A = P0+P1 reg-prefetch (T14, 1 step early),
// B = W gload double-buffered. One barrier per K-step.
// ---------------------------------------------------------------------------
__global__ __launch_bounds__(256) void proj2p(
    const u16* __restrict__ P0, const u16* __restrict__ P1,
    const u16* __restrict__ Wv, const float* __restrict__ bias,
    float* __restrict__ C)
{
    __shared__ u16 As[2][128][32];
    __shared__ u16 Bs[2][64][32];

    const int t = threadIdx.x;
    const int flat = blockIdx.x;
    const int xcd = flat & 7, rr = flat >> 3;
    const int eb = rr & 7, g = rr >> 3;
    const int m0 = (xcd + 8 * g) * 128;
    const int e0 = eb * 64;

    const int w = t >> 6, l = t & 63;
    const int lane16 = l & 15, quad = l >> 4;
    const int wr = (w >> 1) * 64;
    const int wc = (w & 1) * 32;
    const int arow = l >> 2, acol = (l & 3) * 8;
    const int xrow = t >> 2, xc8 = (t & 3) * 8;

    float4v acc[4][2];
    #pragma unroll
    for (int i = 0; i < 4; ++i)
        #pragma unroll
        for (int j = 0; j < 2; ++j)
            acc[i][j] = (float4v){0.f, 0.f, 0.f, 0.f};

    ushort8 pa[2], pb[2];

#define P2_LOADP(k0) do { \
        _Pragma("unroll") \
        for (int i = 0; i < 2; ++i) { \
            size_t gi = (size_t)(m0 + xrow + i * 64) * 512 + (k0) + xc8; \
            pa[i] = *(const ushort8*)(P0 + gi); \
            pb[i] = *(const ushort8*)(P1 + gi); \
        } } while (0)

    P2_LOADP(0);
    gload_lds16(Wv + (size_t)(e0 + w * 16 + arow) * 512 + 0 + acol, &Bs[0][w * 16][0]);

    #pragma unroll
    for (int c = 0; c < 16; ++c) {
        const int cur = c & 1;
        WAIT_VM(0);

        #pragma unroll
        for (int i = 0; i < 2; ++i) {
            ushort8 o;
            #pragma unroll
            for (int j = 0; j < 8; ++j)
                o[j] = f2bf(bf2f(pa[i][j]) + bf2f(pb[i][j]));
            *(ushort8*)&As[cur][xrow + i * 64][xc8] = o;
        }
        WAIT_LGKM0;
        BARRIER;

        short8 af[4], bfr[2];
        #pragma unroll
        for (int i = 0; i < 4; ++i)
            af[i] = *(const short8*)&As[cur][wr + i * 16 + lane16][quad * 8];
        #pragma unroll
        for (int j = 0; j < 2; ++j)
            bfr[j] = *(const short8*)&Bs[cur][wc + j * 16 + lane16][quad * 8];

        if (c + 1 < 16) {
            P2_LOADP((c + 1) * 32);
            gload_lds16(Wv + (size_t)(e0 + w * 16 + arow) * 512 + (c + 1) * 32 + acol,
                        &Bs[cur ^ 1][w * 16][0]);
        }

        __builtin_amdgcn_s_setprio(1);
        #pragma unroll
        for (int i = 0; i < 4; ++i)
            #pragma unroll
            for (int j = 0; j < 2; ++j)
                acc[i][j] = __builtin_amdgcn_mfma_f32_16x16x32_bf16(
                    af[i], bfr[j], acc[i][j], 0, 0, 0);
        __builtin_amdgcn_s_setprio(0);
    }
#undef P2_LOADP

    float bj[2];
    #pragma unroll
    for (int j = 0; j < 2; ++j) bj[j] = bias[e0 + wc + j * 16 + lane16];

    #pragma unroll
    for (int i = 0; i < 4; ++i)
        #pragma unroll
        for (int j = 0; j < 2; ++j) {
            int e = e0 + wc + j * 16 + lane16;
            #pragma unroll
            for (int r = 0; r < 4; ++r) {
                int mrow = m0 + wr + i * 16 + quad * 4 + r;
                C[(size_t)mrow * D_ + e] = acc[i][j][r] + bj[j];
            }
        }
}

// ---------------------------------------------------------------------------
// attn v8: v6 pipeline + batched fragment loads + QK-before-V-wait.
// 512 thr = 8 waves (ns owns 16 n-rows, ms splits the 32-m chunk).
// Per chunk c (2 barriers, counted vmcnt):
//   QK(c): per 4-head group {load 8 kf -> regs; 8 MFMA}   [no V-wait yet]
//   VM(4) drain V(c); commit vreg -> Vs
//   softmax (tree sum) -> Ps (f2bf_fast)
//   issue V(c+1) reg loads; LGKM0; BAR1
//   issue Kg(c+2) -> Ks[cur]
//   PV(c): per 4-head group {load 4 pf + 8 vf -> regs; 8 MFMA}
//   VM(8) drain Kg(c+1); LGKM0; BAR2
// Vs/Ps stride 36 u16 (conflict-free). LDS 140,288 B. grid 256, flat&7=(b,z).
// ---------------------------------------------------------------------------
__global__ __launch_bounds__(512, 2) void attn_mfma8(
    const u16* __restrict__ Qp, const u16* __restrict__ Kp,
    const u16* __restrict__ Vpt, u16* __restrict__ A0)
{
    __shared__ u16 Ks[2][32][520];     // 66,560 B double-buffered K
    __shared__ u16 Vs[512][36];        // 36,864 B (stride-36: clean banks)
    __shared__ u16 Ps[4][8][16][36];   // 36,864 B pair-shared P per n-tile

    const int t = threadIdx.x;
    const int w = t >> 6, l = t & 63;
    const int lane16 = l & 15, quad = l >> 4;
    const int ns = w >> 1, ms = w & 1;

    const int flat = blockIdx.x;
    const int xcd  = flat & 7;
    const int b = xcd >> 1;            // (b, z) pinned to one XCD
    const int z = xcd & 1;
    const int n0 = (flat >> 3) * 64 + ns * 16;   // this wave-pair's 16 rows
    const int seg  = N_ / 2;
    const int mbeg = z * seg;
    u16* A = A0 + (size_t)z * ((size_t)B_ * N_ * D_);

    const u16* Kb = Kp + (size_t)b * N_ * D_;
    const int vd0 = t >> 2, vpart = (t & 3) * 8;
    const u16* Vsrc = Vpt + (size_t)(b * D_) * N_ + vpart;

    // Q fragments: 8 heads x k=64, A-operand layout, persistent (64 VGPRs)
    short8 qfrag[8][2];
    {
        const u16* qb = Qp + ((size_t)(b * N_ + n0 + lane16) * D_ + quad * 8);
        #pragma unroll
        for (int h = 0; h < 8; ++h)
            #pragma unroll
            for (int dc = 0; dc < 2; ++dc)
                qfrag[h][dc] = *(const short8*)(qb + h * 64 + dc * 32);
    }

    float4v aacc[8][2];                // 8 heads x 2 owned d-tiles (64 regs)
    #pragma unroll
    for (int h = 0; h < 8; ++h)
        #pragma unroll
        for (int dt = 0; dt < 2; ++dt)
            aacc[h][dt] = (float4v){0.f, 0.f, 0.f, 0.f};

    ushort8 vreg[4];                   // V prefetch registers (16 VGPRs)
    const int nch = seg / 32;          // 32 chunks

    // ---- prologue: Kg(0), Vl(0), Kg(1); drain Kg(0); barrier ----
    #pragma unroll
    for (int i = 0; i < 4; ++i)
        gload_lds16(Kb + (size_t)(mbeg + w * 4 + i) * D_ + l * 8,
                    &Ks[0][w * 4 + i][0]);
    #pragma unroll
    for (int i = 0; i < 4; ++i)
        vreg[i] = *(const ushort8*)(Vsrc + (size_t)(i * 128 + vd0) * N_ + mbeg);
    #pragma unroll
    for (int i = 0; i < 4; ++i)
        gload_lds16(Kb + (size_t)(mbeg + 32 + w * 4 + i) * D_ + l * 8,
                    &Ks[1][w * 4 + i][0]);
    WAIT_VM(8);            // drain Kg(0); Vl(0)+Kg(1) stay in flight
    BARRIER;               // all waves' Kg(0) landed

    for (int c = 0; c < nch; ++c) {
        const int cur = c & 1;
        const int mc  = mbeg + c * 32;

        // ---- QK^T first (needs only Ks): batched kf loads per 4 heads ----
        float4v sacc[8];
        #pragma unroll
        for (int h = 0; h < 8; ++h) sacc[h] = (float4v){0.f, 0.f, 0.f, 0.f};
        #pragma unroll
        for (int g2 = 0; g2 < 2; ++g2) {
            short8 kf[4][2];
            #pragma unroll
            for (int hh = 0; hh < 4; ++hh)
                #pragma unroll
                for (int dc = 0; dc < 2; ++dc)
                    kf[hh][dc] = *(const short8*)
                        &Ks[cur][ms * 16 + lane16]
                           [(g2 * 4 + hh) * 64 + dc * 32 + quad * 8];
            __builtin_amdgcn_s_setprio(1);
            #pragma unroll
            for (int hh = 0; hh < 4; ++hh)
                #pragma unroll
                for (int dc = 0; dc < 2; ++dc)
                    sacc[g2 * 4 + hh] = __builtin_amdgcn_mfma_f32_16x16x32_bf16(
                        qfrag[g2 * 4 + hh][dc], kf[hh][dc], sacc[g2 * 4 + hh], 0, 0, 0);
            __builtin_amdgcn_s_setprio(0);
        }

        // ---- drain own V-reg loads(c); commit V(c) to Vs ----
        if (c < nch - 1) { WAIT_VM(4); } else { WAIT_VM(0); }
        #pragma unroll
        for (int i = 0; i < 4; ++i)
            *(ushort8*)&Vs[i * 128 + vd0][vpart] = vreg[i];

        // ---- register heads-softmax (tree sum) -> Ps ----
        #pragma unroll
        for (int r = 0; r < 4; ++r) {
            float p[8];
            #pragma unroll
            for (int h = 0; h < 8; ++h)
                p[h] = __expf(sacc[h][r] * 0.125f);   // 1/sqrt(64)
            float s01 = p[0] + p[1], s23 = p[2] + p[3];
            float s45 = p[4] + p[5], s67 = p[6] + p[7];
            float inv = __builtin_amdgcn_rcpf((s01 + s23) + (s45 + s67));
            #pragma unroll
            for (int h = 0; h < 8; ++h)
                Ps[ns][h][quad * 4 + r][ms * 16 + lane16] = f2bf_fast(p[h] * inv);
        }

        // ---- prefetch V(c+1) into registers ----
        if (c + 1 < nch) {
            #pragma unroll
            for (int i = 0; i < 4; ++i)
                vreg[i] = *(const ushort8*)
                    (Vsrc + (size_t)(i * 128 + vd0) * N_ + mc + 32);
        }

        // ---- Ps+Vs visible; VMEM prefetches stay in flight ----
        WAIT_LGKM0;
        BARRIER;

        // ---- prefetch K(c+2) into the Ks buffer QK(c) just freed ----
        if (c + 2 < nch) {
            #pragma unroll
            for (int i = 0; i < 4; ++i)
                gload_lds16(Kb + (size_t)(mc + 64 + w * 4 + i) * D_ + l * 8,
                            &Ks[cur][w * 4 + i][0]);
        }

        // ---- PV: batched pf/vf loads per 4 heads (12 reads in flight) ----
        #pragma unroll
        for (int g2 = 0; g2 < 2; ++g2) {
            short8 pf[4], vf[4][2];
            #pragma unroll
            for (int hh = 0; hh < 4; ++hh) {
                const int h = g2 * 4 + hh;
                pf[hh] = *(const short8*)&Ps[ns][h][lane16][quad * 8];
                #pragma unroll
                for (int dt = 0; dt < 2; ++dt)
                    vf[hh][dt] = *(const short8*)
                        &Vs[h * 64 + (ms * 2 + dt) * 16 + lane16][quad * 8];
            }
            __builtin_amdgcn_s_setprio(1);
            #pragma unroll
            for (int hh = 0; hh < 4; ++hh)
                #pragma unroll
                for (int dt = 0; dt < 2; ++dt)
                    aacc[g2 * 4 + hh][dt] = __builtin_amdgcn_mfma_f32_16x16x32_bf16(
                        pf[hh], vf[hh][dt], aacc[g2 * 4 + hh][dt], 0, 0, 0);
            __builtin_amdgcn_s_setprio(0);
        }

        // ---- drain own Kg(c+1) before barrier -> QK(c+1) safe ----
        if (c < nch - 1) {
            if (c + 2 < nch) { WAIT_VM(8); } else { WAIT_VM(4); }
            WAIT_LGKM0;
            BARRIER;
        }
    }

    // ---- store partial A (bf16), own d-columns only ----
    #pragma unroll
    for (int h = 0; h < 8; ++h)
        #pragma unroll
        for (int dt = 0; dt < 2; ++dt)
            #pragma unroll
            for (int r = 0; r < 4; ++r) {
                const int n = n0 + quad * 4 + r;
                const int d = h * 64 + (ms * 2 + dt) * 16 + lane16;
                A[(size_t)(b * N_ + n) * D_ + d] = f2bf(aacc[h][dt][r]);
            }
}

// ---------------------------------------------------------------------------
extern "C" void kernel_launch(void* const* d_in, const int* in_sizes, int n_in,
                              void* d_out, int out_size, void* d_ws, size_t ws_size,
                              hipStream_t stream)
{
    const float* Q  = (const float*)d_in[0];
    const float* K  = (const float*)d_in[1];
    const float* V  = (const float*)d_in[2];
    const float* Wq = (const float*)d_in[3];
    const float* bq = (const float*)d_in[4];
    const float* Wo = (const float*)d_in[5];
    const float* bo = (const float*)d_in[6];
    float* out = (float*)d_out;
    u16*   ws  = (u16*)d_ws;

    const size_t NBD = (size_t)B_ * N_ * D_;   // 4,194,304

    const size_t need6 = (6 * NBD + 2 * (size_t)D_ * D_) * sizeof(u16); // 51.4 MB

    if (ws_size >= need6) {
        // Path A: bf16-ify inputs once; proj1 all-gload pipelined.
        u16* S0 = ws;
        u16* S1 = ws + NBD;
        u16* S3 = ws + 3 * NBD;
        u16* Wb = ws + 6 * NBD;            // [Wqb | Wob]

        cvt4<<<dim3((unsigned)(NBD / 2048), 4), dim3(256), 0, stream>>>(
            Q, K, V, Wq, Wo, S0, Wb);

        proj1g<<<dim3(768), dim3(256), 0, stream>>>(S0, Wb, bq, S3);

        attn_mfma8<<<dim3(256), dim3(512), 0, stream>>>(
            S3, S3 + NBD, S3 + 2 * NBD, S0);   // partials -> S0, S1

        proj2p<<<dim3(512), dim3(256), 0, stream>>>(
            S0, S1, Wb + (size_t)D_ * D_, bo, out);
    } else {
        // Path B (43.0 MB): fp32-X reg-prefetch staging in proj1.
        u16* Qp  = ws;
        u16* Kp  = ws + NBD;
        u16* Vpt = ws + 2 * NBD;
        u16* Pa  = ws + 3 * NBD;
        u16* Pb  = ws + 4 * NBD;
        u16* Wb  = ws + 5 * NBD;

        wconv<<<dim3(128, 2), dim3(256), 0, stream>>>(Wq, Wo, Wb);

        proj1f<<<dim3(768), dim3(256), 0, stream>>>(Q, K, V, Wb, bq, Qp);

        attn_mfma8<<<dim3(256), dim3(512), 0, stream>>>(Qp, Kp, Vpt, Pa);

        proj2p<<<dim3(512), dim3(256), 0, stream>>>(
            Pa, Pb, Wb + (size_t)D_ * D_, bo, out);
    }
}